// Round 7
// baseline (147.959 us; speedup 1.0000x reference)
//
#include <hip/hip_runtime.h>
#include <math.h>

#define MM 8
#define SS 4
#define NLEAF 20
#define KINT 19
#define NBR 38                   // total branches: 2 + 18*2
#define P4 (NBR*MM*4)            // float4 count of P region = 1216
#define PFLOATS (P4*4)           // 4864 floats
#define NNODE 39
#define SPT 4                    // sites per thread (register-reuse factor for P)
#define BLK 128                  // threads per block
#define SPB (BLK*SPT)            // 512 sites per block

typedef float v2f __attribute__((ext_vector_type(2)));
typedef float v4f __attribute__((ext_vector_type(4)));

// ---------------- setup: Q build + 304 small expm (fp64), stores P TRANSPOSED ----------------

__device__ __forceinline__ void mat4_mul(const double a[4][4], const double b[4][4], double c[4][4]) {
    #pragma unroll
    for (int i = 0; i < 4; i++)
        #pragma unroll
        for (int j = 0; j < 4; j++) {
            double s = 0.0;
            #pragma unroll
            for (int k = 0; k < 4; k++) s += a[i][k] * b[k][j];
            c[i][j] = s;
        }
}

__global__ void setup_kernel(const float* __restrict__ rates,
                             const float* __restrict__ pi_inv,
                             const float* __restrict__ rho,
                             const float* __restrict__ T,
                             float* __restrict__ ws)   // [NBR][MM][4][4] P^T, then pi[MM][4]
{
    int tid = blockIdx.x * blockDim.x + threadIdx.x;
    if (tid >= NBR * MM) return;
    int m = tid & 7;
    int k = tid >> 3;

    // pi = inv_stereographic_projection(pi_inv)^2
    double y0 = pi_inv[m*3+0], y1 = pi_inv[m*3+1], y2 = pi_inv[m*3+2];
    double ns  = y0*y0 + y1*y1 + y2*y2;
    double inv = 1.0 / (ns + 1.0);
    double p[4] = {2.0*y0*inv, 2.0*y1*inv, 2.0*y2*inv, (ns-1.0)*inv};
    #pragma unroll
    for (int i = 0; i < 4; i++) p[i] *= p[i];

    if (k == 0) {
        #pragma unroll
        for (int i = 0; i < 4; i++) ws[PFLOATS + m*4 + i] = (float)p[i];
    }

    // Q from squared rates
    double r[6];
    #pragma unroll
    for (int i = 0; i < 6; i++) { double v = rates[m*6+i]; r[i] = v*v; }
    double Q[4][4] = {};
    Q[0][1]=r[0]; Q[0][2]=r[1]; Q[0][3]=r[2]; Q[1][2]=r[3]; Q[1][3]=r[4]; Q[2][3]=r[5];
    #pragma unroll
    for (int i = 0; i < 4; i++)
        #pragma unroll
        for (int j = i+1; j < 4; j++) Q[j][i] = Q[i][j];
    #pragma unroll
    for (int i = 0; i < 4; i++)
        #pragma unroll
        for (int j = 0; j < 4; j++) Q[i][j] *= p[j];
    double emut = 0.0;
    #pragma unroll
    for (int i = 0; i < 4; i++) {
        double rs = 0.0;
        #pragma unroll
        for (int j = 0; j < 4; j++) if (j != i) rs += Q[i][j];
        Q[i][i] = -rs;
        emut += p[i] * rs;
    }
    emut = fmax(emut, 1e-9);
    double scq = (double)rho[m] / emut;

    // branch length for branch k (caterpillar)
    double t;
    if      (k == 0) t = T[0*NNODE + NLEAF];
    else if (k == 1) t = T[1*NNODE + NLEAF];
    else {
        int j     = k >> 1;                       // 1..18
        int node  = NLEAF + j;
        int child = (k & 1) ? (j + 1) : (NLEAF - 1 + j);
        t = T[child*NNODE + node];
    }

    double A[4][4];
    #pragma unroll
    for (int i = 0; i < 4; i++)
        #pragma unroll
        for (int j = 0; j < 4; j++) A[i][j] = Q[i][j] * scq * t;

    // expm: scale to norm <= 2^-4, Taylor(9), square back
    double nrm = 0.0;
    #pragma unroll
    for (int i = 0; i < 4; i++) {
        double rs = 0.0;
        #pragma unroll
        for (int j = 0; j < 4; j++) rs += fabs(A[i][j]);
        nrm = fmax(nrm, rs);
    }
    int s = 0;
    if (nrm > 0.0625) s = (int)ceil(log2(nrm * 16.0));
    if (s < 0) s = 0;
    if (s > 60) s = 60;
    double scl = ldexp(1.0, -s);
    double B[4][4];
    #pragma unroll
    for (int i = 0; i < 4; i++)
        #pragma unroll
        for (int j = 0; j < 4; j++) B[i][j] = A[i][j] * scl;

    double E[4][4];
    #pragma unroll
    for (int i = 0; i < 4; i++)
        #pragma unroll
        for (int j = 0; j < 4; j++) E[i][j] = (i == j) ? 1.0 : 0.0;
    for (int kk = 9; kk >= 1; --kk) {
        double Tm[4][4];
        mat4_mul(B, E, Tm);
        double ik = 1.0 / (double)kk;
        #pragma unroll
        for (int i = 0; i < 4; i++)
            #pragma unroll
            for (int j = 0; j < 4; j++) E[i][j] = ((i == j) ? 1.0 : 0.0) + Tm[i][j] * ik;
    }
    for (int q = 0; q < s; q++) {
        double Tm[4][4];
        mat4_mul(E, E, Tm);
        #pragma unroll
        for (int i = 0; i < 4; i++)
            #pragma unroll
            for (int j = 0; j < 4; j++) E[i][j] = Tm[i][j];
    }

    // TRANSPOSED store: Pout[d*4 + c] = E[c][d]  => float4 at offset d is column d of P
    float* Pout = ws + (k*MM + m) * 16;
    #pragma unroll
    for (int d = 0; d < 4; d++)
        #pragma unroll
        for (int c = 0; c < 4; c++) Pout[d*4+c] = (float)E[c][d];
}

// ---------------- main: 4 sites/thread, all 8 mixtures; each LDS P-column read feeds 4 sites ----------------

#define SHUF(v,a,b) __builtin_shufflevector((v),(v),(a),(b))

// result[c] = sum_d col_d[c] * x[d];  outputs pair-packed: lo={r0,r1}, hi={r2,r3}
__device__ __forceinline__ void matvx(const v4f& c0, const v4f& c1, const v4f& c2, const v4f& c3,
                                      const v4f& x, v2f& lo, v2f& hi)
{
    v2f l = SHUF(c0,0,1) * SHUF(x,0,0);
    v2f h = SHUF(c0,2,3) * SHUF(x,0,0);
    l = __builtin_elementwise_fma(SHUF(c1,0,1), SHUF(x,1,1), l);
    h = __builtin_elementwise_fma(SHUF(c1,2,3), SHUF(x,1,1), h);
    l = __builtin_elementwise_fma(SHUF(c2,0,1), SHUF(x,2,2), l);
    h = __builtin_elementwise_fma(SHUF(c2,2,3), SHUF(x,2,2), h);
    l = __builtin_elementwise_fma(SHUF(c3,0,1), SHUF(x,3,3), l);
    h = __builtin_elementwise_fma(SHUF(c3,2,3), SHUF(x,3,3), h);
    lo = l; hi = h;
}

// same but operand vector is the pair-packed state {alo=(A0,A1), ahi=(A2,A3)}
__device__ __forceinline__ void matvs(const v4f& c0, const v4f& c1, const v4f& c2, const v4f& c3,
                                      v2f alo, v2f ahi, v2f& lo, v2f& hi)
{
    v2f l = SHUF(c0,0,1) * SHUF(alo,0,0);
    v2f h = SHUF(c0,2,3) * SHUF(alo,0,0);
    l = __builtin_elementwise_fma(SHUF(c1,0,1), SHUF(alo,1,1), l);
    h = __builtin_elementwise_fma(SHUF(c1,2,3), SHUF(alo,1,1), h);
    l = __builtin_elementwise_fma(SHUF(c2,0,1), SHUF(ahi,0,0), l);
    h = __builtin_elementwise_fma(SHUF(c2,2,3), SHUF(ahi,0,0), h);
    l = __builtin_elementwise_fma(SHUF(c3,0,1), SHUF(ahi,1,1), l);
    h = __builtin_elementwise_fma(SHUF(c3,2,3), SHUF(ahi,1,1), h);
    lo = l; hi = h;
}

__global__ __launch_bounds__(BLK) void phylo_kernel(const float* __restrict__ X,
                                                    const float* __restrict__ ws,
                                                    float* __restrict__ out,
                                                    int batch)
{
    __shared__ v4f Pl[P4 + MM];
    const v4f* __restrict__ w4 = (const v4f*)ws;
    for (int idx = threadIdx.x; idx < P4 + MM; idx += BLK) Pl[idx] = w4[idx];
    __syncthreads();

    const int t    = threadIdx.x;
    const int base = blockIdx.x * SPB;

    // 4 sites per thread: base + t + 128k  (lane-consecutive => coalesced X/out)
    const v4f* __restrict__ xp[SPT];
    #pragma unroll
    for (int k = 0; k < SPT; k++) {
        int s = base + t + BLK*k;
        if (s >= batch) s = batch - 1;
        xp[k] = (const v4f*)X + (size_t)s * 20;
    }

    v2f lo[SPT][MM], hi[SPT][MM];    // 128 VGPR of state

    // ---- step 0: node 20 = (leaf0, leaf1) ----
    v4f XA[SPT], XB[SPT];
    #pragma unroll
    for (int k = 0; k < SPT; k++) { XA[k] = xp[k][0]; XB[k] = xp[k][1]; }
    #pragma unroll
    for (int m = 0; m < MM; m++) {
        const v4f* __restrict__ P0 = &Pl[(0*MM + m)*4];
        const v4f* __restrict__ P1 = &Pl[(1*MM + m)*4];
        v4f a0=P0[0], a1=P0[1], a2=P0[2], a3=P0[3];
        v4f e0=P1[0], e1=P1[1], e2=P1[2], e3=P1[3];
        #pragma unroll
        for (int k = 0; k < SPT; k++) {
            v2f tl, th, ul, uh;
            matvx(a0,a1,a2,a3, XA[k], tl, th);
            matvx(e0,e1,e2,e3, XB[k], ul, uh);
            lo[k][m] = tl*ul; hi[k][m] = th*uh;
        }
    }

    // ---- steps 1..18: node 20+j = (internal 19+j, leaf j+1); double-buffered X ----
    #pragma unroll
    for (int k = 0; k < SPT; k++) XA[k] = xp[k][2];     // leaf for step j=1
    #pragma unroll 1
    for (int j = 1; j < KINT; j++) {
        if (j < KINT - 1) {
            #pragma unroll
            for (int k = 0; k < SPT; k++) XB[k] = xp[k][j + 2];  // prefetch next leaf
        }
        const v4f* __restrict__ PI = &Pl[(2*j*MM)*4];   // internal-child block
        const v4f* __restrict__ PL = PI + MM*4;         // leaf-child block
        #pragma unroll
        for (int m = 0; m < MM; m++) {
            v4f ci0=PI[m*4+0], ci1=PI[m*4+1], ci2=PI[m*4+2], ci3=PI[m*4+3];
            v4f cl0=PL[m*4+0], cl1=PL[m*4+1], cl2=PL[m*4+2], cl3=PL[m*4+3];
            #pragma unroll
            for (int k = 0; k < SPT; k++) {             // each column read feeds 4 sites
                v2f tl, th, ul, uh;
                matvs(ci0,ci1,ci2,ci3, lo[k][m], hi[k][m], tl, th);
                matvx(cl0,cl1,cl2,cl3, XA[k], ul, uh);
                lo[k][m] = tl*ul; hi[k][m] = th*uh;
            }
        }
        #pragma unroll
        for (int k = 0; k < SPT; k++) XA[k] = XB[k];
    }

    // ---- epilogue: out[site, m] = sum_c A[c] * pi[m][c] ----
    #pragma unroll
    for (int k = 0; k < SPT; k++) {
        float r[MM];
        #pragma unroll
        for (int m = 0; m < MM; m++) {
            v4f pim = Pl[P4 + m];
            v2f s = __builtin_elementwise_fma(hi[k][m], SHUF(pim,2,3), lo[k][m] * SHUF(pim,0,1));
            r[m] = s.x + s.y;
        }
        int st = base + t + BLK*k;
        if (st < batch) {
            v4f* __restrict__ o4 = (v4f*)(out + (size_t)st * MM);
            o4[0] = (v4f){r[0], r[1], r[2], r[3]};
            o4[1] = (v4f){r[4], r[5], r[6], r[7]};
        }
    }
}

// ---------------- launch ----------------

extern "C" void kernel_launch(void* const* d_in, const int* in_sizes, int n_in,
                              void* d_out, int out_size, void* d_ws, size_t ws_size,
                              hipStream_t stream)
{
    const float* X      = (const float*)d_in[0];
    const float* rates  = (const float*)d_in[1];
    const float* pi_inv = (const float*)d_in[2];
    const float* rho    = (const float*)d_in[3];
    const float* T      = (const float*)d_in[4];
    float* out = (float*)d_out;
    float* ws  = (float*)d_ws;

    int batch = in_sizes[0] / (NLEAF * SS);

    hipLaunchKernelGGL(setup_kernel, dim3(1), dim3(320), 0, stream,
                       rates, pi_inv, rho, T, ws);

    int grid = (batch + SPB - 1) / SPB;
    hipLaunchKernelGGL(phylo_kernel, dim3(grid), dim3(BLK), 0, stream,
                       X, ws, out, batch);
}